// Round 3
// baseline (70.760 us; speedup 1.0000x reference)
//
#include <hip/hip_runtime.h>

// CumulativeFlattenedLinear: per-64-timestep-window projection (C=16 -> O=16,
// per-s weight slice, first ND=16 slots zero) + causal cumsum in window + bias.
//
// v3: lane = s (window == wave). Each wave owns an o-chunk of 8 outputs and
// REGISTER-RESIDENT weights wreg[8][16] = w[o][c][lane] (128 VGPRs), pinned
// with asm so the compiler can't sink the loads into the window loop (the
// v1/v2 failure mode: VGPR=44 proved x/w were re-loaded per o from cache ->
// latency-bound, VALUBusy 8%).
// Per window: 16 coalesced dword x-loads, 128 FMA, 8 DPP 64-lane scans,
// 8 coalesced dword stores. No LDS. Even/odd waves in a block process the
// same windows for the two o-chunks -> x's 2nd read is an L1 hit; HBM traffic
// = 64 MiB x + 64 MiB out -> ~20 us floor.

#define CC 16
#define TT 131072
#define OO 16
#define NK 48
#define ND 16
#define GG 2048          // windows per batch row
#define NWIN 16384       // total windows (B * GG)
#define OCH 8            // outputs per wave
#define NWAVE 3072       // 768 blocks * 4 waves
#define WPW 11           // windows per wave: ceil(16384 / 1536)

// 64-lane inclusive prefix sum via DPP (verified in R1).
#define SCAN_STEP(CTRL, RMASK)                                                  \
  {                                                                             \
    int t_ = __builtin_amdgcn_update_dpp(0, __float_as_int(v), (CTRL), (RMASK), \
                                         0xf, true);                            \
    v += __int_as_float(t_);                                                    \
  }

__device__ __forceinline__ float wave_scan64(float v) {
  SCAN_STEP(0x111, 0xf)  // row_shr:1
  SCAN_STEP(0x112, 0xf)  // row_shr:2
  SCAN_STEP(0x114, 0xf)  // row_shr:4
  SCAN_STEP(0x118, 0xf)  // row_shr:8
  SCAN_STEP(0x142, 0xa)  // row_bcast15
  SCAN_STEP(0x143, 0xc)  // row_bcast31
  return v;
}

__global__ __launch_bounds__(256, 3) void cfl_kernel(
    const float* __restrict__ x, const float* __restrict__ weight,
    const float* __restrict__ bias, float* __restrict__ out) {
  const int tid = threadIdx.x;
  const int lane = tid & 63;
  const int wid = tid >> 6;

  const int gwave = blockIdx.x * 4 + wid;   // 0..3071
  const int o0 = (gwave & 1) * OCH;         // o-chunk: 0 or 8
  const int n0 = (gwave >> 1) * WPW;        // first window

  // Register-resident per-lane weight slice: wreg[oo][c] = w[o0+oo][c][lane]
  // (zero for the ND discard slots, lane < 16). Pinned so it can't be sunk.
  float wreg[OCH][CC];
#pragma unroll
  for (int oo = 0; oo < OCH; ++oo) {
#pragma unroll
    for (int c = 0; c < CC; ++c) {
      float wv = 0.f;
      if (lane >= ND) wv = weight[(o0 + oo) * (CC * NK) + c * NK + (lane - ND)];
      asm volatile("" : "+v"(wv));
      wreg[oo][c] = wv;
    }
  }

  float bo[OCH];
#pragma unroll
  for (int oo = 0; oo < OCH; ++oo) bo[oo] = bias[o0 + oo];

  for (int k = 0; k < WPW; ++k) {
    const int n = n0 + k;
    if (n >= NWIN) break;
    const int b = n >> 11;       // window / GG
    const int g = n & (GG - 1);

    const float* xb = x + (size_t)b * CC * TT + g * 64 + lane;
    float xv[CC];
#pragma unroll
    for (int c = 0; c < CC; ++c) xv[c] = xb[(size_t)c * TT];

    float p[OCH];
#pragma unroll
    for (int oo = 0; oo < OCH; ++oo) p[oo] = 0.f;
#pragma unroll
    for (int c = 0; c < CC; ++c)
#pragma unroll
      for (int oo = 0; oo < OCH; ++oo)
        p[oo] = fmaf(xv[c], wreg[oo][c], p[oo]);

    float* ob = out + (size_t)b * OO * TT + g * 64 + lane;
#pragma unroll
    for (int oo = 0; oo < OCH; ++oo) {
      float cs = wave_scan64(p[oo]);
      ob[(size_t)(o0 + oo) * TT] = cs + bo[oo];
    }
  }
}

extern "C" void kernel_launch(void* const* d_in, const int* in_sizes, int n_in,
                              void* d_out, int out_size, void* d_ws, size_t ws_size,
                              hipStream_t stream) {
  const float* x = (const float*)d_in[0];
  const float* weight = (const float*)d_in[1];
  const float* bias = (const float*)d_in[2];
  float* out = (float*)d_out;

  // 3072 waves (768 blocks): even/odd waves = o-chunks 0/1 on the same windows.
  cfl_kernel<<<768, 256, 0, stream>>>(x, weight, bias, out);
}